// Round 11
// baseline (414.980 us; speedup 1.0000x reference)
//
#include <hip/hip_runtime.h>
#include <math.h>

#define NB 4096
#define NR 49
#define NS 50
#define ND 512
#define NK 100
#define NT 7            // n-tiles of 16 cols (112 >= 100); wave w owns tile w
#define KSTEPS 16       // 512 / 32
#define FRAGS (NT * KSTEPS * 64 * 8)   // 57344 ushorts (114688 B) per weight matrix

typedef __attribute__((ext_vector_type(8))) short short8;
typedef __attribute__((ext_vector_type(4))) float f32x4;

__device__ __forceinline__ unsigned short f32_bf16(float f) {
    union { float f; unsigned u; } x; x.f = f;
    return (unsigned short)((x.u + 0x7fffu + ((x.u >> 16) & 1u)) >> 16);  // RNE
}
__device__ __forceinline__ float bf16_f32(unsigned short h) {
    union { unsigned u; float f; } x; x.u = ((unsigned)h) << 16;
    return x.f;
}
__device__ __forceinline__ unsigned cvt_pk_bf16(float lo, float hi) {
    unsigned r;
    asm("v_cvt_pk_bf16_f32 %0, %1, %2" : "=v"(r) : "v"(lo), "v"(hi));
    return r;
}
__device__ __forceinline__ float fast_tanh(float x) {
    const float ax = fabsf(x);
    const float e = __expf(2.f * ax);            // inf for large ax -> r = 1
    const float r = 1.f - 2.f / (e + 1.f);
    return copysignf(r, x);
}

// ---------------------------------------------------------------------------
// Pre-pass: 2 weight matrices [512][100] f32 -> bf16 MFMA B-fragments.
// (Only w_Vi_0 / w_Vt_1 needed: broadcast conditioning branches cancel in
//  softmax; the two attention passes are fully independent.)
// frag(t, gk): lane l holds W[k = gk*32 + (l>>4)*8 + j][col = t*16 + (l&15)].
// ---------------------------------------------------------------------------
__global__ void preswz_kernel(const float* __restrict__ w0, const float* __restrict__ w1,
                              unsigned short* __restrict__ ws)
{
    const int l  = threadIdx.x;          // 64
    const int gk = blockIdx.x & 15;
    const int t  = blockIdx.x >> 4;      // 0..6
    const int m  = blockIdx.y;           // 0..1
    const float* W = m ? w1 : w0;
    const int col = t * 16 + (l & 15);
    const int k0  = gk * 32 + (l >> 4) * 8;
    unsigned short* o = ws + (size_t)m * FRAGS + ((size_t)(t * 16 + gk) * 64 + l) * 8;
#pragma unroll
    for (int j = 0; j < 8; ++j) {
        float v = (col < NK) ? W[(size_t)(k0 + j) * NK + col] : 0.f;
        o[j] = f32_bf16(v);
    }
}

// ---------------------------------------------------------------------------
// Main kernel: ONE block per batch (both passes), 512 threads (8 waves),
// 2 blocks/CU, cap-128 regs for deep load pipelining.
// Pipeline: stage I (unrolled, 2 load-batches) | GEMM0 | prefetch T->regs
// (hides under epilogue+softmax+wsum0) | softmax0 | wsum0 (LDS) | T regs->LDS
// | GEMM1 | softmax1 | wsum1 -> out. vi carried in a register.
// ---------------------------------------------------------------------------
struct SM {
    short buf[NS * ND];      // 51200 B: bf16 feature tile [50 rows][512 cols]
    float part[NT][64];      // per-wave (n-tile) row partials
    float P[64];
};

__global__ __launch_bounds__(512, 4) void coattn_main(
    const float* __restrict__ ifeat, const float* __restrict__ tfeat,
    const float* __restrict__ wPi0, const float* __restrict__ bPi0,
    const float* __restrict__ wPi1, const float* __restrict__ bPi1,
    const unsigned short* __restrict__ wsW, float* __restrict__ out)
{
    __shared__ SM sm;
    const int b = blockIdx.x, tid = threadIdx.x;
    const int lane = tid & 63, wid = tid >> 6;   // wid 0..6 = n-tile; wid 7 stages/wsums
    const int colg = lane & 15, g = lane >> 4;
    const int wch = tid >> 3, wlo = tid & 7;     // wsum column addressing

    const float* ig = ifeat + (size_t)b * NR * ND;
    const float* tg = tfeat + (size_t)b * NS * ND;

    // row/swizzle precompute for GEMM A-reads (row clamped per pass below)
    const f32x4 zero4 = {0.f, 0.f, 0.f, 0.f};

    // ======== Phase A: stage I -> LDS (3136 items; 2 explicit load batches) ====
#define STG_ITEM(SRC, U, GUARD)                                                   \
    {                                                                             \
        const int it = tid + ((U) << 9);                                          \
        if (GUARD) {                                                              \
            const int r = it >> 6, c = it & 63;                                   \
            const float* p = (SRC) + (r << 9) + (c << 3);                         \
            const float4 a  = *reinterpret_cast<const float4*>(p);                \
            const float4 b4 = *reinterpret_cast<const float4*>(p + 4);            \
            uint4 v;                                                              \
            v.x = cvt_pk_bf16(a.x, a.y);   v.y = cvt_pk_bf16(a.z, a.w);           \
            v.z = cvt_pk_bf16(b4.x, b4.y); v.w = cvt_pk_bf16(b4.z, b4.w);         \
            *reinterpret_cast<uint4*>(&sm.buf[(r << 9) + ((c ^ (r & 7)) << 3)]) = v; \
        }                                                                         \
    }
    // batch 1: items 0..3 (unconditional), batch 2: items 4..6
    STG_ITEM(ig, 0, true) STG_ITEM(ig, 1, true) STG_ITEM(ig, 2, true) STG_ITEM(ig, 3, true)
    STG_ITEM(ig, 4, true) STG_ITEM(ig, 5, true) STG_ITEM(ig, 6, tid < 64)   // 3136 = 6*512+64
    __syncthreads();

    // ======== Phase B: GEMM0 (wave w < 7 owns n-tile w; rows clamped to 48) ====
    f32x4 acc[4] = {zero4, zero4, zero4, zero4};
    {
        int arow_[4], rswz_[4];
#pragma unroll
        for (int rt = 0; rt < 4; ++rt) {
            const int r0 = rt * 16 + colg;
            arow_[rt] = (r0 < NR - 1) ? r0 : (NR - 1);
            rswz_[rt] = arow_[rt] & 7;
        }
        if (wid < NT) {
            const unsigned short* wl = wsW + ((size_t)wid * KSTEPS * 64 + lane) * 8;
#pragma unroll
            for (int ks = 0; ks < KSTEPS; ++ks) {
                const short8 w = *reinterpret_cast<const short8*>(wl + ks * 512);
                const int q0 = (ks << 2) + g;
#pragma unroll
                for (int rt = 0; rt < 4; ++rt) {
                    const short8 a = *reinterpret_cast<const short8*>(
                        &sm.buf[(arow_[rt] << 9) + ((q0 ^ rswz_[rt]) << 3)]);
                    acc[rt] = __builtin_amdgcn_mfma_f32_16x16x32_bf16(a, w, acc[rt], 0, 0, 0);
                }
            }
        }
    }

    // ======== Phase C: prefetch T -> regs (loads hide under D/E phases) ========
    uint4 tr[7];
#pragma unroll
    for (int u = 0; u < 7; ++u) {
        const int it = tid + (u << 9);
        if (u < 6 || tid < 128) {                 // 3200 = 6*512+128
            const int r = it >> 6, c = it & 63;
            const float* p = tg + (r << 9) + (c << 3);
            const float4 a  = *reinterpret_cast<const float4*>(p);
            const float4 b4 = *reinterpret_cast<const float4*>(p + 4);
            tr[u].x = cvt_pk_bf16(a.x, a.y);   tr[u].y = cvt_pk_bf16(a.z, a.w);
            tr[u].z = cvt_pk_bf16(b4.x, b4.y); tr[u].w = cvt_pk_bf16(b4.z, b4.w);
        }
    }

    // ======== Phase D: epilogue0 -> part[] ====================================
    if (wid < NT) {
        const int col = wid * 16 + colg;
        const float w = (col < NK) ? wPi0[col] : 0.f;
        float sp[4][4];
#pragma unroll
        for (int rt = 0; rt < 4; ++rt)
#pragma unroll
            for (int i = 0; i < 4; ++i)
                sp[rt][i] = fast_tanh(acc[rt][i]) * w;
#pragma unroll
        for (int off = 1; off < 16; off <<= 1)
#pragma unroll
            for (int rt = 0; rt < 4; ++rt)
#pragma unroll
                for (int i = 0; i < 4; ++i)
                    sp[rt][i] += __shfl_xor(sp[rt][i], off);
        if (colg == 0) {
#pragma unroll
            for (int rt = 0; rt < 4; ++rt)
#pragma unroll
                for (int i = 0; i < 4; ++i)
                    sm.part[wid][rt * 16 + g * 4 + i] = sp[rt][i];
        }
    }
    __syncthreads();

    if (tid < 64) {   // softmax over R
        float v = (tid < NR) ? bPi0[tid] : 0.f;
#pragma unroll
        for (int w = 0; w < NT; ++w) v += sm.part[w][tid];
        v = (tid < NR) ? v : -3.0e38f;
        float mx = v;
#pragma unroll
        for (int off = 32; off; off >>= 1) mx = fmaxf(mx, __shfl_xor(mx, off));
        const float e = (tid < NR) ? __expf(v - mx) : 0.f;
        float su = e;
#pragma unroll
        for (int off = 32; off; off >>= 1) su += __shfl_xor(su, off);
        sm.P[tid] = e / su;
    }
    __syncthreads();

    // ======== Phase E: wsum0 from LDS bf16 -> vi ==============================
    float vi = 0.f;
    for (int r = 0; r < NR; ++r) {
        const unsigned short u = (unsigned short)
            sm.buf[(r << 9) + ((wch ^ (r & 7)) << 3) + wlo];
        vi += sm.P[r] * bf16_f32(u);
    }
    __syncthreads();   // buf reads complete before T overwrite

    // ======== Phase F: T regs -> LDS ==========================================
#pragma unroll
    for (int u = 0; u < 7; ++u) {
        const int it = tid + (u << 9);
        if (u < 6 || tid < 128) {
            const int r = it >> 6, c = it & 63;
            *reinterpret_cast<uint4*>(&sm.buf[(r << 9) + ((c ^ (r & 7)) << 3)]) = tr[u];
        }
    }
    __syncthreads();

    // ======== Phase G: GEMM1 ==================================================
#pragma unroll
    for (int rt = 0; rt < 4; ++rt) acc[rt] = zero4;
    {
        int arow_[4], rswz_[4];
#pragma unroll
        for (int rt = 0; rt < 4; ++rt) {
            const int r0 = rt * 16 + colg;
            arow_[rt] = (r0 < NS - 1) ? r0 : (NS - 1);
            rswz_[rt] = arow_[rt] & 7;
        }
        if (wid < NT) {
            const unsigned short* wl = wsW + (size_t)FRAGS
                                     + ((size_t)wid * KSTEPS * 64 + lane) * 8;
#pragma unroll
            for (int ks = 0; ks < KSTEPS; ++ks) {
                const short8 w = *reinterpret_cast<const short8*>(wl + ks * 512);
                const int q0 = (ks << 2) + g;
#pragma unroll
                for (int rt = 0; rt < 4; ++rt) {
                    const short8 a = *reinterpret_cast<const short8*>(
                        &sm.buf[(arow_[rt] << 9) + ((q0 ^ rswz_[rt]) << 3)]);
                    acc[rt] = __builtin_amdgcn_mfma_f32_16x16x32_bf16(a, w, acc[rt], 0, 0, 0);
                }
            }
        }
    }

    // ======== epilogue1 -> part[] =============================================
    if (wid < NT) {
        const int col = wid * 16 + colg;
        const float w = (col < NK) ? wPi1[NK + col] : 0.f;
        float sp[4][4];
#pragma unroll
        for (int rt = 0; rt < 4; ++rt)
#pragma unroll
            for (int i = 0; i < 4; ++i)
                sp[rt][i] = fast_tanh(acc[rt][i]) * w;
#pragma unroll
        for (int off = 1; off < 16; off <<= 1)
#pragma unroll
            for (int rt = 0; rt < 4; ++rt)
#pragma unroll
                for (int i = 0; i < 4; ++i)
                    sp[rt][i] += __shfl_xor(sp[rt][i], off);
        if (colg == 0) {
#pragma unroll
            for (int rt = 0; rt < 4; ++rt)
#pragma unroll
                for (int i = 0; i < 4; ++i)
                    sm.part[wid][rt * 16 + g * 4 + i] = sp[rt][i];
        }
    }
    __syncthreads();

    if (tid < 64) {   // softmax over S
        float v = (tid < NS) ? bPi1[tid] : 0.f;
#pragma unroll
        for (int w = 0; w < NT; ++w) v += sm.part[w][tid];
        v = (tid < NS) ? v : -3.0e38f;
        float mx = v;
#pragma unroll
        for (int off = 32; off; off >>= 1) mx = fmaxf(mx, __shfl_xor(mx, off));
        const float e = (tid < NS) ? __expf(v - mx) : 0.f;
        float su = e;
#pragma unroll
        for (int off = 32; off; off >>= 1) su += __shfl_xor(su, off);
        sm.P[tid] = e / su;
    }
    __syncthreads();

    // ======== wsum1 from LDS + final write ====================================
    {
        float v = 0.f;
        for (int r = 0; r < NS; ++r) {
            const unsigned short u = (unsigned short)
                sm.buf[(r << 9) + ((wch ^ (r & 7)) << 3) + wlo];
            v += sm.P[r] * bf16_f32(u);
        }
        out[(size_t)b * ND + tid] = vi + v;
    }
#undef STG_ITEM
}

extern "C" void kernel_launch(void* const* d_in, const int* in_sizes, int n_in,
                              void* d_out, int out_size, void* d_ws, size_t ws_size,
                              hipStream_t stream) {
    const float* ifeat = (const float*)d_in[0];
    const float* tfeat = (const float*)d_in[1];
    const float* wVi0  = (const float*)d_in[2];
    const float* wPi0  = (const float*)d_in[4];
    const float* bPi0  = (const float*)d_in[5];
    const float* wVt1  = (const float*)d_in[7];
    const float* wPi1  = (const float*)d_in[8];
    const float* bPi1  = (const float*)d_in[9];
    float* outp = (float*)d_out;
    unsigned short* wsW = (unsigned short*)d_ws;   // 2*114688 = 229376 B

    hipLaunchKernelGGL(preswz_kernel, dim3(NT * KSTEPS, 2), dim3(64), 0, stream,
                       wVi0, wVt1, wsW);
    hipLaunchKernelGGL(coattn_main, dim3(NB), dim3(512), 0, stream,
                       ifeat, tfeat, wPi0, bPi0, wPi1, bPi1, wsW, outp);
}

// Round 12
// 308.791 us; speedup vs baseline: 1.3439x; 1.3439x over previous
//
#include <hip/hip_runtime.h>
#include <math.h>

#define NB 4096
#define NR 49
#define NS 50
#define ND 512
#define NK 100
#define NT 7            // n-tiles of 16 cols (112 >= 100)
#define KSTEPS 16       // 512 / 32
#define FRAGS (NT * KSTEPS * 64 * 8)   // 57344 ushorts (114688 B) per weight matrix

typedef __attribute__((ext_vector_type(8))) short short8;
typedef __attribute__((ext_vector_type(4))) float f32x4;

__device__ __forceinline__ unsigned short f32_bf16(float f) {
    union { float f; unsigned u; } x; x.f = f;
    return (unsigned short)((x.u + 0x7fffu + ((x.u >> 16) & 1u)) >> 16);  // RNE
}
__device__ __forceinline__ unsigned cvt_pk_bf16(float lo, float hi) {
    unsigned r;
    asm("v_cvt_pk_bf16_f32 %0, %1, %2" : "=v"(r) : "v"(lo), "v"(hi));
    return r;
}
__device__ __forceinline__ float fast_tanh(float x) {
    const float ax = fabsf(x);
    const float e = __expf(2.f * ax);            // inf for large ax -> r = 1
    const float r = 1.f - 2.f / (e + 1.f);
    return copysignf(r, x);
}
// async global->LDS DMA, 16B/lane, zero VGPR cost; LDS dest is wave-uniform
// base + lane*16 (linear), swizzle lives in the per-lane global address.
__device__ __forceinline__ void load_lds16(const float* g, float* l) {
    __builtin_amdgcn_global_load_lds(
        (const __attribute__((address_space(1))) unsigned int*)(const void*)g,
        (__attribute__((address_space(3))) unsigned int*)(void*)l, 16, 0, 0);
}
#define FENCE() asm volatile("" ::: "memory")
#define BARR()  do { FENCE(); __builtin_amdgcn_s_barrier(); FENCE(); } while (0)
#define WAITV(N) asm volatile("s_waitcnt vmcnt(" #N ")" ::: "memory")

// ---------------------------------------------------------------------------
// Pre-pass: 2 weight matrices [512][100] f32 -> bf16 MFMA B-fragments.
// (Only w_Vi_0 / w_Vt_1 needed: broadcast conditioning branches cancel in
//  softmax; the two attention passes are fully independent.)
// frag(t, gk): lane l holds W[k = gk*32 + (l>>4)*8 + j][col = t*16 + (l&15)].
// ---------------------------------------------------------------------------
__global__ void preswz_kernel(const float* __restrict__ w0, const float* __restrict__ w1,
                              unsigned short* __restrict__ ws)
{
    const int l  = threadIdx.x;          // 64
    const int gk = blockIdx.x & 15;
    const int t  = blockIdx.x >> 4;      // 0..6
    const int m  = blockIdx.y;           // 0..1
    const float* W = m ? w1 : w0;
    const int col = t * 16 + (l & 15);
    const int k0  = gk * 32 + (l >> 4) * 8;
    unsigned short* o = ws + (size_t)m * FRAGS + ((size_t)(t * 16 + gk) * 64 + l) * 8;
#pragma unroll
    for (int j = 0; j < 8; ++j) {
        float v = (col < NK) ? W[(size_t)(k0 + j) * NK + col] : 0.f;
        o[j] = f32_bf16(v);
    }
}

// ---------------------------------------------------------------------------
// Main kernel: one block per (batch, pass), 512 threads (8 waves).
// Features stream HBM -> LDS as f32 via async global_load_lds (4 chunks of
// [50][128] f32 through 2 buffers, counted vmcnt + raw barriers: loads for
// chunk k+1 stay in flight while chunk k is consumed). GEMM converts f32->bf16
// at fragment build. Wave w = (pair q = w>>1, row-half mh = w&1): owns n-tiles
// {2q, 2q+1} (q=3: one) x row-tiles {2mh, 2mh+1}. Softmax -> global-f32
// weighted sum -> atomicAdd (out pre-zeroed; 2 commutative adds/elem).
// ---------------------------------------------------------------------------
struct SM {
    float bufA[50 * 128];    // 25600 B f32 chunk (linear rows of 512 B)
    float bufB[50 * 128];
    float part[8][64];       // per-wave row partials (rows mh*32..+32 valid)
    float P[64];
};

__global__ __launch_bounds__(512, 4) void coattn_main(
    const float* __restrict__ ifeat, const float* __restrict__ tfeat,
    const float* __restrict__ wPi0, const float* __restrict__ bPi0,
    const float* __restrict__ wPi1, const float* __restrict__ bPi1,
    const unsigned short* __restrict__ wsW, float* __restrict__ out)
{
    __shared__ SM sm;
    const int pass = blockIdx.x & 1;
    const int b    = blockIdx.x >> 1;
    const int tid  = threadIdx.x;

    const float* feat = pass ? (tfeat + (size_t)b * NS * ND) : (ifeat + (size_t)b * NR * ND);
    const int nrows  = pass ? NS : NR;
    const int nclamp = nrows - 1;
    const unsigned short* wsR = wsW + (size_t)pass * FRAGS;
    const float* wPiRow = pass ? (wPi1 + NK) : wPi0;
    const float* bvec   = pass ? bPi1 : bPi0;

    const int lane = tid & 63, wid = tid >> 6;
    const int colg = lane & 15, g = lane >> 4;
    const int q  = wid >> 1;          // tile-pair 0..3
    const int mh = wid & 1;           // row-half
    const int t0 = q * 2;
    const int two = (q < 3);          // q==3 owns only tile 6

    int arow_[2], aswz_[2];
#pragma unroll
    for (int rl = 0; rl < 2; ++rl) {
        const int r0 = (mh * 2 + rl) * 16 + colg;
        arow_[rl] = (r0 < nclamp) ? r0 : nclamp;
        aswz_[rl] = arow_[rl] & 7;
    }
    const unsigned short* wl0 = wsR + ((size_t)t0 * 16 * 64 + lane) * 8;
    const unsigned short* wl1 = wl0 + (size_t)16 * 64 * 8;

    // -- staging: instr j (0..24) covers LDS rows 2j,2j+1; lane: row = 2j+(l>>5),
    //    c16 = l&31; global source pre-XOR-swizzled so readers can de-swizzle.
#define ISSUE(CP, BUF)                                                          \
    do {                                                                        \
        _Pragma("unroll") for (int s = 0; s < 3; ++s) {                         \
            const int j = wid + (s << 3);                                       \
            const int row = 2 * j + (lane >> 5);                                \
            const int grow = (row < nrows) ? row : nclamp;                      \
            const int c16 = lane & 31;                                          \
            load_lds16(feat + (grow << 9) + ((CP) << 7) + ((c16 ^ (row & 7)) << 2), \
                       sm.BUF + j * 256);                                       \
        }                                                                       \
        if (wid == 0) {                                                         \
            const int row = 48 + (lane >> 5);                                   \
            const int grow = (row < nrows) ? row : nclamp;                      \
            const int c16 = lane & 31;                                          \
            load_lds16(feat + (grow << 9) + ((CP) << 7) + ((c16 ^ (row & 7)) << 2), \
                       sm.BUF + 24 * 256);                                      \
        }                                                                       \
    } while (0)
#define WAITC() do { if (wid == 0) { WAITV(4); } else { WAITV(3); } } while (0)

    f32x4 acc[2][2];
#pragma unroll
    for (int rl = 0; rl < 2; ++rl)
#pragma unroll
        for (int tl = 0; tl < 2; ++tl) acc[rl][tl] = f32x4{0.f, 0.f, 0.f, 0.f};

#define GEMMP(LB, CP)                                                           \
    do {                                                                        \
        _Pragma("unroll") for (int ksl = 0; ksl < 4; ++ksl) {                   \
            const int ks = (CP) * 4 + ksl;                                      \
            const short8 wf0 = *reinterpret_cast<const short8*>(wl0 + ks * 512); \
            short8 wf1 = {};                                                    \
            if (two) wf1 = *reinterpret_cast<const short8*>(wl1 + ks * 512);    \
            _Pragma("unroll") for (int rl = 0; rl < 2; ++rl) {                  \
                const int c16 = (ksl << 3) + (g << 1);                          \
                const float4 fa = *reinterpret_cast<const float4*>(             \
                    &(LB)[arow_[rl] * 128 + ((c16 ^ aswz_[rl]) << 2)]);         \
                const float4 fb = *reinterpret_cast<const float4*>(             \
                    &(LB)[arow_[rl] * 128 + (((c16 + 1) ^ aswz_[rl]) << 2)]);   \
                uint4 ap;                                                       \
                ap.x = cvt_pk_bf16(fa.x, fa.y); ap.y = cvt_pk_bf16(fa.z, fa.w); \
                ap.z = cvt_pk_bf16(fb.x, fb.y); ap.w = cvt_pk_bf16(fb.z, fb.w); \
                const short8 a = *reinterpret_cast<const short8*>(&ap);         \
                acc[rl][0] = __builtin_amdgcn_mfma_f32_16x16x32_bf16(a, wf0, acc[rl][0], 0, 0, 0); \
                if (two)                                                        \
                    acc[rl][1] = __builtin_amdgcn_mfma_f32_16x16x32_bf16(a, wf1, acc[rl][1], 0, 0, 0); \
            }                                                                   \
        }                                                                       \
    } while (0)

    // ---- pipelined stream: 4 chunks, 2 buffers, counted vmcnt
    ISSUE(0, bufA);
    ISSUE(1, bufB);
    WAITC(); BARR();          // chunk0 in LDS (chunk1 still in flight)
    GEMMP(sm.bufA, 0);
    BARR();                   // all waves done reading bufA
    ISSUE(2, bufA);
    WAITC(); BARR();          // chunk1 in LDS (chunk2 in flight)
    GEMMP(sm.bufB, 1);
    BARR();
    ISSUE(3, bufB);
    WAITC(); BARR();          // chunk2 in LDS (chunk3 in flight)
    GEMMP(sm.bufA, 2);
    WAITV(0); BARR();         // chunk3 in LDS
    GEMMP(sm.bufB, 3);

    // ---- epilogue: per-wave row partials (sum over this wave's 1-2 tiles)
    {
        const int c0 = (t0 + 0) * 16 + colg;
        const int c1 = (t0 + 1) * 16 + colg;
        const float w0 = (c0 < NK) ? wPiRow[c0] : 0.f;
        const float w1 = (two && c1 < NK) ? wPiRow[c1] : 0.f;
        float sp[2][4];
#pragma unroll
        for (int rl = 0; rl < 2; ++rl)
#pragma unroll
            for (int i = 0; i < 4; ++i) {
                float v = fast_tanh(acc[rl][0][i]) * w0;
                if (two) v += fast_tanh(acc[rl][1][i]) * w1;
                sp[rl][i] = v;
            }
#pragma unroll
        for (int off = 1; off < 16; off <<= 1)
#pragma unroll
            for (int rl = 0; rl < 2; ++rl)
#pragma unroll
                for (int i = 0; i < 4; ++i)
                    sp[rl][i] += __shfl_xor(sp[rl][i], off);
        if (colg == 0) {
#pragma unroll
            for (int rl = 0; rl < 2; ++rl)
#pragma unroll
                for (int i = 0; i < 4; ++i)
                    sm.part[wid][(mh * 2 + rl) * 16 + g * 4 + i] = sp[rl][i];
        }
    }
    __syncthreads();

    if (tid < 64) {   // softmax over rows; row r lives in waves {2q + (r>=32)}
        const int hb = (tid >= 32) ? 1 : 0;
        float v = (tid < nrows) ? bvec[tid] : 0.f;
#pragma unroll
        for (int qq = 0; qq < 4; ++qq) v += sm.part[2 * qq + hb][tid];
        v = (tid < nrows) ? v : -3.0e38f;
        float mx = v;
#pragma unroll
        for (int off = 32; off; off >>= 1) mx = fmaxf(mx, __shfl_xor(mx, off));
        const float e = (tid < nrows) ? __expf(v - mx) : 0.f;
        float su = e;
#pragma unroll
        for (int off = 32; off; off >>= 1) su += __shfl_xor(su, off);
        sm.P[tid] = e / su;
    }
    __syncthreads();

    // ---- weighted sum: V[tid] = sum_r P[r] * feat[r, tid]  (global f32, L2-hot)
    {
        float v = 0.f;
        const float* fp = feat + tid;
        for (int r = 0; r < nrows; ++r) v += sm.P[r] * fp[r << 9];
        atomicAdd(&out[(size_t)b * ND + tid], v);
    }
#undef ISSUE
#undef WAITC
#undef GEMMP
}

extern "C" void kernel_launch(void* const* d_in, const int* in_sizes, int n_in,
                              void* d_out, int out_size, void* d_ws, size_t ws_size,
                              hipStream_t stream) {
    const float* ifeat = (const float*)d_in[0];
    const float* tfeat = (const float*)d_in[1];
    const float* wVi0  = (const float*)d_in[2];
    const float* wPi0  = (const float*)d_in[4];
    const float* bPi0  = (const float*)d_in[5];
    const float* wVt1  = (const float*)d_in[7];
    const float* wPi1  = (const float*)d_in[8];
    const float* bPi1  = (const float*)d_in[9];
    float* outp = (float*)d_out;
    unsigned short* wsW = (unsigned short*)d_ws;   // 2*114688 = 229376 B

    hipMemsetAsync(outp, 0, (size_t)NB * ND * sizeof(float), stream);
    hipLaunchKernelGGL(preswz_kernel, dim3(NT * KSTEPS, 2), dim3(64), 0, stream,
                       wVi0, wVt1, wsW);
    hipLaunchKernelGGL(coattn_main, dim3(2 * NB), dim3(512), 0, stream,
                       ifeat, tfeat, wPi0, bPi0, wPi1, bPi1, wsW, outp);
}